// Round 7
// baseline (183.960 us; speedup 1.0000x reference)
//
#include <hip/hip_runtime.h>
#include <math.h>

#define HH 1024
#define WW 1024
#define NPLANES 12              // B*C = 4*3
#define PLANE (HH * WW)
#define NTOT (NPLANES * PLANE)

#define TW 64                   // output tile width
#define TH 64                   // output tile height
#define RH 92                   // h1 rows: gy in [y0-14, y0+77]  (phys rows 0..91)
#define RB 78                   // B1/h2 logical rows: gy in [y0-7, y0+70]
#define PH 80                   // pitch (floats), 20 quads, quad-XOR swizzle by (physrow & 3)
// LDS: phys rows 0..91 = h1 (later h2 in rows 0..77); B1 logical rows 0..63 at
// phys rows 92..155; B1 logical rows 64..77 ALIAS h1 phys rows 78..91 (their
// last use is the same P3 iteration that produces the aliasing write).
#define LDSF (156 * PH)         // 49,920 B -> 50,176 alloc -> 3 blocks/CU

typedef float vf4 __attribute__((ext_vector_type(4)));

struct W15 { float w[15]; };

__device__ inline float chain1(float t, float gain, float gamma, float sb,
                               float hr, float br, float ct) {
    t = t * gain;
    t = __builtin_amdgcn_exp2f(gamma * __log2f(t));          // pow(t,gamma), t>=0
    float hi = __fdividef(1.0f, 1.0f + __expf((0.5f - t) * 10.0f));
    t = t + sb * (1.0f - hi) - hr * hi;
    t = fminf(fmaxf(t, 0.0f), 1.0f);
    t = ct * (t - 0.5f) + 0.5f + br;
    return fminf(fmaxf(t, 0.0f), 1.0f);
}

// B1 logical row -> physical LDS row
__device__ inline int b1r(int r) { return (r < 64) ? (92 + r) : (r + 14); }
// swizzled addressing (quad q of phys row pr stored at quad q ^ (pr&3))
__device__ inline int swq(int pr, int q) { return pr * PH + ((q ^ (pr & 3)) << 2); }
__device__ inline int sws(int pr, int j) {
    return pr * PH + ((((j >> 2) ^ (pr & 3)) << 2) | (j & 3));
}

// 16 outputs from a 32-float register window; output j taps f[j+1 .. j+15]
__device__ inline void dot16(const float* f, const W15& wk, float* o) {
#pragma unroll
    for (int j = 0; j < 16; ++j) {
        float a = 0.0f, b = 0.0f;
#pragma unroll
        for (int k = 0; k < 8; ++k)  a += wk.w[k] * f[j + 1 + k];
#pragma unroll
        for (int k = 8; k < 15; ++k) b += wk.w[k] * f[j + 1 + k];
        o[j] = a + b;
    }
}

// ---- XCD-aware tile remap: same-XCD (mod-8) blocks cover contiguous region ---
__device__ inline void tile_map(int& p, int& x0, int& y0, bool& edge) {
    int L = (blockIdx.z * gridDim.y + blockIdx.y) * gridDim.x + blockIdx.x; // 0..3071
    int xcd = L & 7;
    int t   = L >> 3;
    int g   = xcd * 384 + t;          // contiguous 1.5-plane region per XCD
    p = g >> 8;
    int w  = g & 255;
    int ty = w >> 4, tx = w & 15;
    x0 = tx * TW; y0 = ty * TH;
    edge = (tx == 0) || (tx == 15) || (ty == 0) || (ty == 15);
}

// ============ K1: pointwise chain, x -> x1 ====================================
// 32B/thread; nontemporal loads (x is read-once -> don't evict X1 from L2/L3).
__global__ __launch_bounds__(256) void k_point(
    const vf4* __restrict__ x, vf4* __restrict__ o,
    const float* __restrict__ gains,
    const float* __restrict__ pg, const float* __restrict__ psb,
    const float* __restrict__ phr, const float* __restrict__ pbr,
    const float* __restrict__ pct)
{
    int i = blockIdx.x * blockDim.x + threadIdx.x;   // 0 .. NTOT/8-1
    int c = ((i * 8) / PLANE) % 3;                   // PLANE % 8 == 0 -> uniform
    float gain = gains[c];
    float gamma = *pg, sb = *psb, hr = *phr, br = *pbr, ct = *pct;

    vf4 v0 = __builtin_nontemporal_load(x + 2 * i);
    vf4 v1 = __builtin_nontemporal_load(x + 2 * i + 1);
#pragma unroll
    for (int j = 0; j < 4; ++j) {
        v0[j] = chain1(v0[j], gain, gamma, sb, hr, br, ct);
        v1[j] = chain1(v1[j], gain, gamma, sb, hr, br, ct);
    }
    o[2 * i]     = v0;
    o[2 * i + 1] = v1;
}

// ============ K2: double blur from x1 (global) + combine + mask ===============
//  P1: h1 = hblur(x1) global->regs->LDS rows 0..91   (R5 schedule, verified)
//  cc: x1 at tile centers (issued after P1 compute, consumed in P5)
//  P3: B1 = vblur(h1) masked to image; tail rows alias h1 rows 78..91
//      (rotating register window -> zero shift-movs)
//  P4: h2 = hblur(B1) -> LDS rows 0..77              (R5 schedule, verified)
//  P5: B2 = vblur(h2) rotating window; combine + mask + clip + NT store
// =============================================================================
__global__ __launch_bounds__(256, 3) void k_fused(
    const float* __restrict__ x1, float* __restrict__ dst,
    const float* __restrict__ penh,
    const float* __restrict__ psoft, const float* __restrict__ pint,
    const float* __restrict__ prot, const float* __restrict__ phard,
    W15 wk)
{
    __shared__ float lds[LDSF];

    int p, x0, y0; bool edge;
    tile_map(p, x0, y0, edge);
    const int tid = threadIdx.x;
    const int tx  = tid & 63;
    const int ty  = tid >> 6;

    const float* __restrict__ plane = x1 + (size_t)p * PLANE;

    // ---------------- P1: h1 rows straight from global x1 (R5 schedule) -------
    // unit u -> row r = u/5 (gy = y0-14+r), seg s (out cols gx = x0-8+16s+j)
#pragma unroll
    for (int it = 0; it < 2; ++it) {
        int u = tid + 256 * it;
        if (u < RH * 5) {
            int r = u / 5, s = u - 5 * r;
            int gy  = y0 - 14 + r;
            int gxa = x0 + 16 * s - 16;          // 16-aligned window base
            float f[32];
            if (!edge) {
                const float* rp = plane + (size_t)gy * WW + gxa;
#pragma unroll
                for (int i = 0; i < 8; ++i)
                    *(float4*)&f[4 * i] = *(const float4*)(rp + 4 * i);
            } else {
                bool rowin = (unsigned)gy < HH;
                const float* rp = plane + (size_t)(rowin ? gy : 0) * WW;
#pragma unroll
                for (int i = 0; i < 8; ++i) {
                    int gq = gxa + 4 * i;
                    float4 v = make_float4(0.f, 0.f, 0.f, 0.f);
                    if (rowin && gq >= 0 && gq + 3 < WW)   // quads all-in or all-out
                        v = *(const float4*)(rp + gq);
                    *(float4*)&f[4 * i] = v;
                }
            }
            float o[16];
            dot16(f, wk, o);
#pragma unroll
            for (int qq = 0; qq < 4; ++qq)
                *(float4*)&lds[swq(r, 4 * s + qq)] = *(float4*)&o[4 * qq];
        }
    }

    // ---------------- cc: x1 at centers (global; overlaps barrier wait) -------
    float cc[16];
    {
        const float* pc0 = plane + (size_t)(y0 + ty * 16) * WW + (x0 + tx);
#pragma unroll
        for (int jj = 0; jj < 16; ++jj) cc[jj] = pc0[(size_t)jj * WW];
    }
    __syncthreads();

    // ---------------- P3: B1 = vblur(h1); rotating window ---------------------
    // win slot for logical offset k at iteration jj is (jj+k)%15 -> all indices
    // compile-time after unroll: no shift movs, no scratch.
    if (tid < 240) {
        int j = tid % 80, band = tid / 80;
        int rb0 = band * 26;                     // 0, 26, 52
        bool xin = (unsigned)(x0 - 8 + j) < WW;
        float win[15];
#pragma unroll
        for (int k = 0; k < 14; ++k) win[k] = lds[sws(rb0 + k, j)];
#pragma unroll
        for (int jj = 0; jj < 26; ++jj) {
            win[(jj + 14) % 15] = lds[sws(rb0 + jj + 14, j)];
            float a = 0.0f, b = 0.0f;
#pragma unroll
            for (int k = 0; k < 8; ++k)  a += wk.w[k] * win[(jj + k) % 15];
#pragma unroll
            for (int k = 8; k < 15; ++k) b += wk.w[k] * win[(jj + k) % 15];
            float v = a + b;
            if (edge) {
                int gy = y0 - 7 + rb0 + jj;
                if (!((unsigned)gy < HH) || !xin) v = 0.0f;
            }
            lds[sws(b1r(rb0 + jj), j)] = v;      // rl>=64 aliases row just consumed
        }
    }
    __syncthreads();

    // ---------------- P4: h2 = hblur(B1) -> rows 0..77 (R5 schedule) ----------
#pragma unroll
    for (int it = 0; it < 2; ++it) {
        int u = tid + 256 * it;
        if (u < RB * 4) {
            int rb = u >> 2, s = u & 3;          // out cols gx = x0 + 16s + j
            int pb = b1r(rb);
            float f[32];
#pragma unroll
            for (int i = 0; i < 8; ++i)
                *(float4*)&f[4 * i] = *(const float4*)&lds[swq(pb, 4 * s + i)];
            float o[16];
            dot16(f, wk, o);
#pragma unroll
            for (int qq = 0; qq < 4; ++qq)
                *(float4*)&lds[swq(rb, 4 * s + qq)] = *(float4*)&o[4 * qq];
        }
    }
    __syncthreads();

    // ---------------- P5: B2 = vblur(h2); combine + mask + clip + store -------
    const float e     = *penh;
    const float sf    = *psoft;
    const float inten = *pint;
    const float hard  = *phard;
    const float theta = (*prot) * 0.017453292519943295f;
    const float cth = __cosf(theta), sth = __sinf(theta);
    const int   gx    = x0 + tx;
    const float gbase = (-1.0f + 2.0f * (float)gx * (1.0f / (float)(WW - 1))) * cth;
    const float ce    = 1.0f + e;

    // gradient-mask exp is linear in y -> geometric recurrence (1 exp, 15 muls)
    const float dstep = 2.0f / (float)(HH - 1);
    const float gy0n  = -1.0f + (float)(y0 + ty * 16) * dstep;
    float       E     = __expf(hard * (gbase + gy0n * sth));
    const float q     = __expf(hard * sth * dstep);

    const int ry0 = ty * 16;

    float bb[16];
#pragma unroll
    for (int jj = 0; jj < 16; ++jj)
        bb[jj] = lds[sws(b1r(ry0 + jj + 7), tx + 8)];

    float win[15];
#pragma unroll
    for (int k = 0; k < 14; ++k) win[k] = lds[sws(ry0 + k, tx)];

    float* __restrict__ dstP = dst + (size_t)p * PLANE;
#pragma unroll
    for (int jj = 0; jj < 16; ++jj) {
        win[(jj + 14) % 15] = lds[sws(ry0 + jj + 14, tx)];
        float a = 0.0f, b = 0.0f;
#pragma unroll
        for (int k = 0; k < 8; ++k)  a += wk.w[k] * win[(jj + k) % 15];
#pragma unroll
        for (int k = 8; k < 15; ++k) b += wk.w[k] * win[(jj + k) % 15];
        float B2  = a + b;
        float x2c = ce * cc[jj] - e * bb[jj];       // x2 at center
        float bx2 = ce * bb[jj] - e * B2;           // blur(x2) via linearity
        float v   = sf * bx2 + (1.0f - sf) * x2c;
        int   y   = y0 + ry0 + jj;
        float mask = __fdividef(1.0f, 1.0f + E);
        E *= q;
        v = v * (1.0f - inten * mask);
        v = fminf(fmaxf(v, 0.0f), 1.0f);
        __builtin_nontemporal_store(v, &dstP[(size_t)y * WW + gx]);
    }
}

extern "C" void kernel_launch(void* const* d_in, const int* in_sizes, int n_in,
                              void* d_out, int out_size, void* d_ws, size_t ws_size,
                              hipStream_t stream)
{
    const float* x       = (const float*)d_in[0];
    const float* gains   = (const float*)d_in[1];
    const float* p_gamma = (const float*)d_in[2];
    const float* p_sb    = (const float*)d_in[3];
    const float* p_hr    = (const float*)d_in[4];
    const float* p_br    = (const float*)d_in[5];
    const float* p_ct    = (const float*)d_in[6];
    const float* p_enh   = (const float*)d_in[7];
    const float* p_soft  = (const float*)d_in[8];
    const float* p_int   = (const float*)d_in[9];
    const float* p_rot   = (const float*)d_in[10];
    const float* p_hard  = (const float*)d_in[11];

    float* X1 = (float*)d_ws;     // chained input, 50.3 MB

    W15 wk;
    {
        double g[15], sum = 0.0;
        for (int i = 0; i < 15; ++i) { double d = (double)(i - 7); g[i] = exp(-d * d / 18.0); sum += g[i]; }
        for (int i = 0; i < 15; ++i) wk.w[i] = (float)(g[i] / sum);
    }

    // K1: x -> X1 (pointwise chain, memory-bound)
    k_point<<<dim3(NTOT / 8 / 256), dim3(256), 0, stream>>>(
        (const vf4*)x, (vf4*)X1, gains, p_gamma, p_sb, p_hr, p_br, p_ct);

    // K2: X1 -> out (double blur + combine + mask)
    dim3 grid(WW / TW, HH / TH, NPLANES);   // 16 x 16 x 12 (remapped in-kernel)
    k_fused<<<grid, dim3(256), 0, stream>>>(
        X1, (float*)d_out, p_enh, p_soft, p_int, p_rot, p_hard, wk);
}

// Round 8
// 177.019 us; speedup vs baseline: 1.0392x; 1.0392x over previous
//
#include <hip/hip_runtime.h>
#include <math.h>

#define HH 1024
#define WW 1024
#define NPLANES 12              // B*C = 4*3
#define PLANE (HH * WW)
#define NTOT (NPLANES * PLANE)

#define TW 64                   // output tile width
#define TH 64                   // output tile height
#define RH 92                   // h1 rows: gy in [y0-14, y0+77]  (phys rows 0..91)
#define RB 78                   // B1/h2 logical rows: gy in [y0-7, y0+70]
#define PH 80                   // pitch (floats), 20 quads, quad-XOR swizzle by (physrow & 3)
// LDS: phys rows 0..91 = h1 (later h2 in rows 0..77); B1 logical rows 0..63 at
// phys rows 92..155; B1 logical rows 64..77 ALIAS h1 phys rows 78..91 (each such
// write is a same-thread read-then-write of that row in the same P3 iteration;
// with the 5-band split below, ALL aliased rows belong to band 4).
#define LDSF (156 * PH)         // 49,920 B -> 50,176 alloc -> 3 blocks/CU @512thr

typedef float vf4 __attribute__((ext_vector_type(4)));

struct W15 { float w[15]; };

__device__ inline float chain1(float t, float gain, float gamma, float sb,
                               float hr, float br, float ct) {
    t = t * gain;
    t = __builtin_amdgcn_exp2f(gamma * __log2f(t));          // pow(t,gamma), t>=0
    float hi = __fdividef(1.0f, 1.0f + __expf((0.5f - t) * 10.0f));
    t = t + sb * (1.0f - hi) - hr * hi;
    t = fminf(fmaxf(t, 0.0f), 1.0f);
    t = ct * (t - 0.5f) + 0.5f + br;
    return fminf(fmaxf(t, 0.0f), 1.0f);
}

// B1 logical row -> physical LDS row
__device__ inline int b1r(int r) { return (r < 64) ? (92 + r) : (r + 14); }
// swizzled addressing (quad q of phys row pr stored at quad q ^ (pr&3))
__device__ inline int swq(int pr, int q) { return pr * PH + ((q ^ (pr & 3)) << 2); }
__device__ inline int sws(int pr, int j) {
    return pr * PH + ((((j >> 2) ^ (pr & 3)) << 2) | (j & 3));
}

// 16 outputs from a 32-float register window; output j taps f[j+1 .. j+15]
__device__ inline void dot16(const float* f, const W15& wk, float* o) {
#pragma unroll
    for (int j = 0; j < 16; ++j) {
        float a = 0.0f, b = 0.0f;
#pragma unroll
        for (int k = 0; k < 8; ++k)  a += wk.w[k] * f[j + 1 + k];
#pragma unroll
        for (int k = 8; k < 15; ++k) b += wk.w[k] * f[j + 1 + k];
        o[j] = a + b;
    }
}

// ---- XCD-aware tile remap: same-XCD (mod-8) blocks cover contiguous region ---
__device__ inline void tile_map(int& p, int& x0, int& y0, bool& edge) {
    int L = (blockIdx.z * gridDim.y + blockIdx.y) * gridDim.x + blockIdx.x; // 0..3071
    int xcd = L & 7;
    int t   = L >> 3;
    int g   = xcd * 384 + t;          // contiguous 1.5-plane region per XCD
    p = g >> 8;
    int w  = g & 255;
    int ty = w >> 4, tx = w & 15;
    x0 = tx * TW; y0 = ty * TH;
    edge = (tx == 0) || (tx == 15) || (ty == 0) || (ty == 15);
}

// ============ K1: pointwise chain, x -> x1 ====================================
// 32B/thread; nontemporal loads (x is read-once -> don't evict X1 from L2/L3).
__global__ __launch_bounds__(256) void k_point(
    const vf4* __restrict__ x, vf4* __restrict__ o,
    const float* __restrict__ gains,
    const float* __restrict__ pg, const float* __restrict__ psb,
    const float* __restrict__ phr, const float* __restrict__ pbr,
    const float* __restrict__ pct)
{
    int i = blockIdx.x * blockDim.x + threadIdx.x;   // 0 .. NTOT/8-1
    int c = ((i * 8) / PLANE) % 3;                   // PLANE % 8 == 0 -> uniform
    float gain = gains[c];
    float gamma = *pg, sb = *psb, hr = *phr, br = *pbr, ct = *pct;

    vf4 v0 = __builtin_nontemporal_load(x + 2 * i);
    vf4 v1 = __builtin_nontemporal_load(x + 2 * i + 1);
#pragma unroll
    for (int j = 0; j < 4; ++j) {
        v0[j] = chain1(v0[j], gain, gamma, sb, hr, br, ct);
        v1[j] = chain1(v1[j], gain, gamma, sb, hr, br, ct);
    }
    o[2 * i]     = v0;
    o[2 * i + 1] = v1;
}

// ============ K2: double blur from x1 (global) + combine + mask ===============
// 512 threads/block, same 64x64 tile, same LDS layout (3 blocks/CU = 24 waves).
//  P1: h1 = hblur(x1) global->LDS rows 0..91   (460 units, 1/thread)
//  cc: x1 at tile centers, 8 rows/thread (issued before barrier)
//  P3: B1 = vblur(h1); 5 bands {16,16,16,16,14} x 80 cols = 400 threads;
//      band 4 owns all aliased writes (phys 78..91, same-thread RMW)
//  P4: h2 = hblur(B1) -> rows 0..77            (312 units, 1/thread)
//  P5: B2 = vblur(h2), 8 rows/thread; combine + mask + clip + NT store
// =============================================================================
__global__ __launch_bounds__(512, 6) void k_fused(
    const float* __restrict__ x1, float* __restrict__ dst,
    const float* __restrict__ penh,
    const float* __restrict__ psoft, const float* __restrict__ pint,
    const float* __restrict__ prot, const float* __restrict__ phard,
    W15 wk)
{
    __shared__ float lds[LDSF];

    int p, x0, y0; bool edge;
    tile_map(p, x0, y0, edge);
    const int tid = threadIdx.x;
    const int tx  = tid & 63;
    const int ty  = tid >> 6;            // 0..7

    const float* __restrict__ plane = x1 + (size_t)p * PLANE;

    // ---------------- P1: h1 rows straight from global x1 ---------------------
    // unit tid -> row r = tid/5 (gy = y0-14+r), seg s (out cols gx = x0-8+16s+j)
    if (tid < RH * 5) {
        int r = tid / 5, s = tid - 5 * r;
        int gy  = y0 - 14 + r;
        int gxa = x0 + 16 * s - 16;          // 16-aligned window base
        float f[32];
        if (!edge) {
            const float* rp = plane + (size_t)gy * WW + gxa;
#pragma unroll
            for (int i = 0; i < 8; ++i)
                *(float4*)&f[4 * i] = *(const float4*)(rp + 4 * i);
        } else {
            bool rowin = (unsigned)gy < HH;
            const float* rp = plane + (size_t)(rowin ? gy : 0) * WW;
#pragma unroll
            for (int i = 0; i < 8; ++i) {
                int gq = gxa + 4 * i;
                float4 v = make_float4(0.f, 0.f, 0.f, 0.f);
                if (rowin && gq >= 0 && gq + 3 < WW)   // quads all-in or all-out
                    v = *(const float4*)(rp + gq);
                *(float4*)&f[4 * i] = v;
            }
        }
        float o[16];
        dot16(f, wk, o);
#pragma unroll
        for (int qq = 0; qq < 4; ++qq)
            *(float4*)&lds[swq(r, 4 * s + qq)] = *(float4*)&o[4 * qq];
    }

    // ---------------- cc: x1 at centers (global; overlaps barrier wait) -------
    float cc[8];
    {
        const float* pc0 = plane + (size_t)(y0 + ty * 8) * WW + (x0 + tx);
#pragma unroll
        for (int jj = 0; jj < 8; ++jj) cc[jj] = pc0[(size_t)jj * WW];
    }
    __syncthreads();

    // ---------------- P3: B1 = vblur(h1), masked to image support -------------
    // bands {16,16,16,16,14}: bands 0..3 cover rl 0..63 (write phys 92..155,
    // read rows <= 77); band 4 covers rl 64..77 (reads rows 64..91; each write
    // to phys rl+14 follows this thread's read of that same row/col).
    if (tid < 400) {
        int j = tid % 80, band = tid / 80;
        int rb0 = band * 16;                 // 0,16,32,48,64
        int nb  = (band == 4) ? 14 : 16;
        bool xin = (unsigned)(x0 - 8 + j) < WW;
        float win[15];
#pragma unroll
        for (int k = 0; k < 14; ++k) win[k] = lds[sws(rb0 + k, j)];
#pragma unroll
        for (int jj = 0; jj < 16; ++jj) {
            if (jj < nb) {
                win[(jj + 14) % 15] = lds[sws(rb0 + jj + 14, j)];
                float a = 0.0f, b = 0.0f;
#pragma unroll
                for (int k = 0; k < 8; ++k)  a += wk.w[k] * win[(jj + k) % 15];
#pragma unroll
                for (int k = 8; k < 15; ++k) b += wk.w[k] * win[(jj + k) % 15];
                float v = a + b;
                if (edge) {
                    int gy = y0 - 7 + rb0 + jj;
                    if (!((unsigned)gy < HH) || !xin) v = 0.0f;
                }
                lds[sws(b1r(rb0 + jj), j)] = v;
            }
        }
    }
    __syncthreads();

    // ---------------- P4: h2 = hblur(B1) -> rows 0..77, quads 0..15 -----------
    if (tid < RB * 4) {
        int rb = tid >> 2, s = tid & 3;      // out cols gx = x0 + 16s + j
        int pb = b1r(rb);
        float f[32];
#pragma unroll
        for (int i = 0; i < 8; ++i)
            *(float4*)&f[4 * i] = *(const float4*)&lds[swq(pb, 4 * s + i)];
        float o[16];
        dot16(f, wk, o);
#pragma unroll
        for (int qq = 0; qq < 4; ++qq)
            *(float4*)&lds[swq(rb, 4 * s + qq)] = *(float4*)&o[4 * qq];
    }
    __syncthreads();

    // ---------------- P5: B2 = vblur(h2); combine + mask + clip + store -------
    const float e     = *penh;
    const float sf    = *psoft;
    const float inten = *pint;
    const float hard  = *phard;
    const float theta = (*prot) * 0.017453292519943295f;
    const float cth = __cosf(theta), sth = __sinf(theta);
    const int   gx    = x0 + tx;
    const float gbase = (-1.0f + 2.0f * (float)gx * (1.0f / (float)(WW - 1))) * cth;
    const float ce    = 1.0f + e;

    // gradient-mask exp is linear in y -> geometric recurrence (1 exp, 7 muls)
    const float dstep = 2.0f / (float)(HH - 1);
    const float gy0n  = -1.0f + (float)(y0 + ty * 8) * dstep;
    float       E     = __expf(hard * (gbase + gy0n * sth));
    const float q     = __expf(hard * sth * dstep);

    const int ry0 = ty * 8;

    float bb[8];
#pragma unroll
    for (int jj = 0; jj < 8; ++jj)
        bb[jj] = lds[sws(b1r(ry0 + jj + 7), tx + 8)];

    float win[15];
#pragma unroll
    for (int k = 0; k < 14; ++k) win[k] = lds[sws(ry0 + k, tx)];

    float* __restrict__ dstP = dst + (size_t)p * PLANE;
#pragma unroll
    for (int jj = 0; jj < 8; ++jj) {
        win[(jj + 14) % 15] = lds[sws(ry0 + jj + 14, tx)];
        float a = 0.0f, b = 0.0f;
#pragma unroll
        for (int k = 0; k < 8; ++k)  a += wk.w[k] * win[(jj + k) % 15];
#pragma unroll
        for (int k = 8; k < 15; ++k) b += wk.w[k] * win[(jj + k) % 15];
        float B2  = a + b;
        float x2c = ce * cc[jj] - e * bb[jj];       // x2 at center
        float bx2 = ce * bb[jj] - e * B2;           // blur(x2) via linearity
        float v   = sf * bx2 + (1.0f - sf) * x2c;
        int   y   = y0 + ry0 + jj;
        float mask = __fdividef(1.0f, 1.0f + E);
        E *= q;
        v = v * (1.0f - inten * mask);
        v = fminf(fmaxf(v, 0.0f), 1.0f);
        __builtin_nontemporal_store(v, &dstP[(size_t)y * WW + gx]);
    }
}

extern "C" void kernel_launch(void* const* d_in, const int* in_sizes, int n_in,
                              void* d_out, int out_size, void* d_ws, size_t ws_size,
                              hipStream_t stream)
{
    const float* x       = (const float*)d_in[0];
    const float* gains   = (const float*)d_in[1];
    const float* p_gamma = (const float*)d_in[2];
    const float* p_sb    = (const float*)d_in[3];
    const float* p_hr    = (const float*)d_in[4];
    const float* p_br    = (const float*)d_in[5];
    const float* p_ct    = (const float*)d_in[6];
    const float* p_enh   = (const float*)d_in[7];
    const float* p_soft  = (const float*)d_in[8];
    const float* p_int   = (const float*)d_in[9];
    const float* p_rot   = (const float*)d_in[10];
    const float* p_hard  = (const float*)d_in[11];

    float* X1 = (float*)d_ws;     // chained input, 50.3 MB

    W15 wk;
    {
        double g[15], sum = 0.0;
        for (int i = 0; i < 15; ++i) { double d = (double)(i - 7); g[i] = exp(-d * d / 18.0); sum += g[i]; }
        for (int i = 0; i < 15; ++i) wk.w[i] = (float)(g[i] / sum);
    }

    // K1: x -> X1 (pointwise chain, memory-bound)
    k_point<<<dim3(NTOT / 8 / 256), dim3(256), 0, stream>>>(
        (const vf4*)x, (vf4*)X1, gains, p_gamma, p_sb, p_hr, p_br, p_ct);

    // K2: X1 -> out (double blur + combine + mask), 512 threads/block
    dim3 grid(WW / TW, HH / TH, NPLANES);   // 16 x 16 x 12 (remapped in-kernel)
    k_fused<<<grid, dim3(512), 0, stream>>>(
        X1, (float*)d_out, p_enh, p_soft, p_int, p_rot, p_hard, wk);
}

// Round 9
// 175.423 us; speedup vs baseline: 1.0487x; 1.0091x over previous
//
#include <hip/hip_runtime.h>
#include <math.h>

#define HH 1024
#define WW 1024
#define NPLANES 12              // B*C = 4*3
#define PLANE (HH * WW)

#define TW 64                   // output tile width
#define TH 64                   // output tile height
#define RH 92                   // h1 rows: gy in [y0-14, y0+77]  (phys rows 0..91)
#define RB 78                   // B1/h2 logical rows: gy in [y0-7, y0+70]
#define PH 80                   // H pitch (floats), 20 quads, quad-XOR swizzle by (row & 3)
// LDS map (floats):
//   [0      .. 7359 ]  H     : h1 rows 0..91 (pitch 80); later h2 in rows 0..77
//   [7360   .. 12479]  B1    : logical rows 0..63 at phys 92..155 (pitch 80);
//                              logical rows 64..77 ALIAS H phys rows 78..91
//   [7360   .. 11775]  A     : 46 x 96 chained-input staging (two passes);
//                              lives only P0a->P1a / P0b->P1b, BEFORE P3 writes
//                              B1 -> overlap is safe (barrier-separated).
#define AOFF 7360
#define APITCH 96               // 24 quads; group-XOR swizzle (q&24)|((q^r)&7)
#define LDSF (156 * PH)         // 49,920 B -> 50,176 alloc -> 3 blocks/CU @512thr

struct W15 { float w[15]; };

__device__ inline float chain1(float t, float gain, float gamma, float sb,
                               float hr, float br, float ct) {
    t = t * gain;
    t = __builtin_amdgcn_exp2f(gamma * __log2f(t));          // pow(t,gamma), t>=0
    float hi = __fdividef(1.0f, 1.0f + __expf((0.5f - t) * 10.0f));
    t = t + sb * (1.0f - hi) - hr * hi;
    t = fminf(fmaxf(t, 0.0f), 1.0f);
    t = ct * (t - 0.5f) + 0.5f + br;
    return fminf(fmaxf(t, 0.0f), 1.0f);
}

// B1 logical row -> physical LDS row
__device__ inline int b1r(int r) { return (r < 64) ? (92 + r) : (r + 14); }
// H swizzled addressing (quad q of phys row pr stored at quad q ^ (pr&3))
__device__ inline int swq(int pr, int q) { return pr * PH + ((q ^ (pr & 3)) << 2); }
__device__ inline int sws(int pr, int j) {
    return pr * PH + ((((j >> 2) ^ (pr & 3)) << 2) | (j & 3));
}
// A addressing: quad q (0..23) of row r stored at quad (q&24)|((q^r)&7)
__device__ inline int aq(int r, int q) {
    return AOFF + r * APITCH + (((q & 24) | ((q ^ r) & 7)) << 2);
}
__device__ inline int as(int r, int c) {           // scalar col c (0..95)
    int q = c >> 2;
    return AOFF + r * APITCH + ((((q & 24) | ((q ^ r) & 7)) << 2) | (c & 3));
}

// 16 outputs from a 32-float register window; output j taps f[j+1 .. j+15]
__device__ inline void dot16(const float* f, const W15& wk, float* o) {
#pragma unroll
    for (int j = 0; j < 16; ++j) {
        float a = 0.0f, b = 0.0f;
#pragma unroll
        for (int k = 0; k < 8; ++k)  a += wk.w[k] * f[j + 1 + k];
#pragma unroll
        for (int k = 8; k < 15; ++k) b += wk.w[k] * f[j + 1 + k];
        o[j] = a + b;
    }
}

// ---- XCD-aware tile remap: same-XCD (mod-8) blocks cover contiguous region ---
__device__ inline void tile_map(int& p, int& x0, int& y0, bool& edge) {
    int L = (blockIdx.z * gridDim.y + blockIdx.y) * gridDim.x + blockIdx.x; // 0..3071
    int xcd = L & 7;
    int t   = L >> 3;
    int g   = xcd * 384 + t;          // contiguous 1.5-plane region per XCD
    p = g >> 8;
    int w  = g & 255;
    int ty = w >> 4, tx = w & 15;
    x0 = tx * TW; y0 = ty * TH;
    edge = (tx == 0) || (tx == 15) || (ty == 0) || (ty == 15);
}

// P0: chain(x) for one 46-row vertical half into A (zero outside image)
__device__ inline void stage_A(float* lds, const float* __restrict__ plane,
                               int x0, int gyb, bool edge, int tid,
                               float gain, float gamma, float sb,
                               float hr, float br, float ct) {
#pragma unroll
    for (int k = 0; k < 2; ++k) {
        int u = tid + 512 * k;                   // < 1024 < 1104, always active
        int r = u / 24, q = u - 24 * r;
        int gy = gyb + r;
        int gq = x0 - 16 + 4 * q;                // 4-aligned: quad all-in/all-out
        float4 v = make_float4(0.f, 0.f, 0.f, 0.f);
        if (!edge || ((unsigned)gy < HH && gq >= 0 && gq + 3 < WW)) {
            v = *(const float4*)(plane + (size_t)gy * WW + gq);
            float* pv = (float*)&v;
#pragma unroll
            for (int j = 0; j < 4; ++j)
                pv[j] = chain1(pv[j], gain, gamma, sb, hr, br, ct);
        }
        *(float4*)&lds[aq(r, q)] = v;
    }
    if (tid < 46 * 24 - 1024) {                  // tail: 80 threads
        int u = tid + 1024;
        int r = u / 24, q = u - 24 * r;
        int gy = gyb + r;
        int gq = x0 - 16 + 4 * q;
        float4 v = make_float4(0.f, 0.f, 0.f, 0.f);
        if (!edge || ((unsigned)gy < HH && gq >= 0 && gq + 3 < WW)) {
            v = *(const float4*)(plane + (size_t)gy * WW + gq);
            float* pv = (float*)&v;
#pragma unroll
            for (int j = 0; j < 4; ++j)
                pv[j] = chain1(pv[j], gain, gamma, sb, hr, br, ct);
        }
        *(float4*)&lds[aq(r, q)] = v;
    }
}

// P1: h1 rows (one 46-row half) from A; no edge handling needed (A zero-padded)
__device__ inline void hblur_half(float* lds, int hrow0, int tid, const W15& wk) {
    if (tid < 46 * 5) {
        int r = tid / 5, s = tid - 5 * r;        // A row r, out cols 16s..16s+15
        float f[32];
#pragma unroll
        for (int i = 0; i < 8; ++i)
            *(float4*)&f[4 * i] = *(const float4*)&lds[aq(r, 4 * s + i)];
        float o[16];
        dot16(f, wk, o);
        int hr_ = hrow0 + r;
#pragma unroll
        for (int qq = 0; qq < 4; ++qq)
            *(float4*)&lds[swq(hr_, 4 * s + qq)] = *(float4*)&o[4 * qq];
    }
}

// =============================================================================
// Fully fused single kernel (512 threads, 64x64 tile, 3 blocks/CU):
//  P0a: chain(x) rows y0-14..y0+31 -> A      | bar
//  P1a: h1 rows 0..45 = hblur(A); cc for ty<4 from A | bar
//  P0b: chain(x) rows y0+32..y0+77 -> A      | bar
//  P1b: h1 rows 46..91; cc for ty>=4 from A  | bar
//  P3 : B1 = vblur(h1) masked to image (5 bands; band 4 owns aliased rows) | bar
//  P4 : h2 = hblur(B1) -> H rows 0..77       | bar
//  P5 : B2 = vblur(h2); x2c=(1+e)cc-e*bb; bx2=(1+e)bb-e*B2;
//       out = clip((s*bx2+(1-s)*x2c)*(1-intensity*mask)), NT store
// =============================================================================
__global__ __launch_bounds__(512, 6) void k_fused(
    const float* __restrict__ x, float* __restrict__ dst,
    const float* __restrict__ gains,
    const float* __restrict__ pg, const float* __restrict__ psb,
    const float* __restrict__ phr, const float* __restrict__ pbr,
    const float* __restrict__ pct, const float* __restrict__ penh,
    const float* __restrict__ psoft, const float* __restrict__ pint,
    const float* __restrict__ prot, const float* __restrict__ phard,
    W15 wk)
{
    __shared__ float lds[LDSF];

    int p, x0, y0; bool edge;
    tile_map(p, x0, y0, edge);
    const int tid = threadIdx.x;
    const int tx  = tid & 63;
    const int ty  = tid >> 6;            // 0..7

    const float* __restrict__ plane = x + (size_t)p * PLANE;
    const float gain  = gains[p % 3];
    const float gamma = *pg, sb = *psb, hrp = *phr, br = *pbr, ct = *pct;

    float cc[8];

    // ---------------- P0a / P1a (+cc rows 0..31) ------------------------------
    stage_A(lds, plane, x0, y0 - 14, edge, tid, gain, gamma, sb, hrp, br, ct);
    __syncthreads();
    hblur_half(lds, 0, tid, wk);
    if (ty < 4) {                        // centers gy = y0 + ty*8 + jj, A row +14
#pragma unroll
        for (int jj = 0; jj < 8; ++jj)
            cc[jj] = lds[as(ty * 8 + jj + 14, tx + 16)];
    }
    __syncthreads();

    // ---------------- P0b / P1b (+cc rows 32..63) -----------------------------
    stage_A(lds, plane, x0, y0 + 32, edge, tid, gain, gamma, sb, hrp, br, ct);
    __syncthreads();
    hblur_half(lds, 46, tid, wk);
    if (ty >= 4) {                       // A row = ty*8 + jj + 14 - 46
#pragma unroll
        for (int jj = 0; jj < 8; ++jj)
            cc[jj] = lds[as(ty * 8 + jj - 32, tx + 16)];
    }
    __syncthreads();

    // ---------------- P3: B1 = vblur(h1), masked to image support -------------
    // bands {16,16,16,16,14}: bands 0..3 cover rl 0..63 (write phys 92..155,
    // read rows <= 77); band 4 covers rl 64..77 (reads rows 64..91; each write
    // to phys rl+14 follows this thread's read of that same row/col).
    if (tid < 400) {
        int j = tid % 80, band = tid / 80;
        int rb0 = band * 16;                 // 0,16,32,48,64
        int nb  = (band == 4) ? 14 : 16;
        bool xin = (unsigned)(x0 - 8 + j) < WW;
        float win[15];
#pragma unroll
        for (int k = 0; k < 14; ++k) win[k] = lds[sws(rb0 + k, j)];
#pragma unroll
        for (int jj = 0; jj < 16; ++jj) {
            if (jj < nb) {
                win[(jj + 14) % 15] = lds[sws(rb0 + jj + 14, j)];
                float a = 0.0f, b = 0.0f;
#pragma unroll
                for (int k = 0; k < 8; ++k)  a += wk.w[k] * win[(jj + k) % 15];
#pragma unroll
                for (int k = 8; k < 15; ++k) b += wk.w[k] * win[(jj + k) % 15];
                float v = a + b;
                if (edge) {
                    int gy = y0 - 7 + rb0 + jj;
                    if (!((unsigned)gy < HH) || !xin) v = 0.0f;
                }
                lds[sws(b1r(rb0 + jj), j)] = v;
            }
        }
    }
    __syncthreads();

    // ---------------- P4: h2 = hblur(B1) -> rows 0..77, quads 0..15 -----------
    if (tid < RB * 4) {
        int rb = tid >> 2, s = tid & 3;      // out cols gx = x0 + 16s + j
        int pb = b1r(rb);
        float f[32];
#pragma unroll
        for (int i = 0; i < 8; ++i)
            *(float4*)&f[4 * i] = *(const float4*)&lds[swq(pb, 4 * s + i)];
        float o[16];
        dot16(f, wk, o);
#pragma unroll
        for (int qq = 0; qq < 4; ++qq)
            *(float4*)&lds[swq(rb, 4 * s + qq)] = *(float4*)&o[4 * qq];
    }
    __syncthreads();

    // ---------------- P5: B2 = vblur(h2); combine + mask + clip + store -------
    const float e     = *penh;
    const float sf    = *psoft;
    const float inten = *pint;
    const float hard  = *phard;
    const float theta = (*prot) * 0.017453292519943295f;
    const float cth = __cosf(theta), sth = __sinf(theta);
    const int   gx    = x0 + tx;
    const float gbase = (-1.0f + 2.0f * (float)gx * (1.0f / (float)(WW - 1))) * cth;
    const float ce    = 1.0f + e;

    // gradient-mask exp is linear in y -> geometric recurrence (1 exp, 7 muls)
    const float dstep = 2.0f / (float)(HH - 1);
    const float gy0n  = -1.0f + (float)(y0 + ty * 8) * dstep;
    float       E     = __expf(hard * (gbase + gy0n * sth));
    const float q     = __expf(hard * sth * dstep);

    const int ry0 = ty * 8;

    float bb[8];
#pragma unroll
    for (int jj = 0; jj < 8; ++jj)
        bb[jj] = lds[sws(b1r(ry0 + jj + 7), tx + 8)];

    float win[15];
#pragma unroll
    for (int k = 0; k < 14; ++k) win[k] = lds[sws(ry0 + k, tx)];

    float* __restrict__ dstP = dst + (size_t)p * PLANE;
#pragma unroll
    for (int jj = 0; jj < 8; ++jj) {
        win[(jj + 14) % 15] = lds[sws(ry0 + jj + 14, tx)];
        float a = 0.0f, b = 0.0f;
#pragma unroll
        for (int k = 0; k < 8; ++k)  a += wk.w[k] * win[(jj + k) % 15];
#pragma unroll
        for (int k = 8; k < 15; ++k) b += wk.w[k] * win[(jj + k) % 15];
        float B2  = a + b;
        float x2c = ce * cc[jj] - e * bb[jj];       // x2 at center
        float bx2 = ce * bb[jj] - e * B2;           // blur(x2) via linearity
        float v   = sf * bx2 + (1.0f - sf) * x2c;
        int   y   = y0 + ry0 + jj;
        float mask = __fdividef(1.0f, 1.0f + E);
        E *= q;
        v = v * (1.0f - inten * mask);
        v = fminf(fmaxf(v, 0.0f), 1.0f);
        __builtin_nontemporal_store(v, &dstP[(size_t)y * WW + gx]);
    }
}

extern "C" void kernel_launch(void* const* d_in, const int* in_sizes, int n_in,
                              void* d_out, int out_size, void* d_ws, size_t ws_size,
                              hipStream_t stream)
{
    const float* x       = (const float*)d_in[0];
    const float* gains   = (const float*)d_in[1];
    const float* p_gamma = (const float*)d_in[2];
    const float* p_sb    = (const float*)d_in[3];
    const float* p_hr    = (const float*)d_in[4];
    const float* p_br    = (const float*)d_in[5];
    const float* p_ct    = (const float*)d_in[6];
    const float* p_enh   = (const float*)d_in[7];
    const float* p_soft  = (const float*)d_in[8];
    const float* p_int   = (const float*)d_in[9];
    const float* p_rot   = (const float*)d_in[10];
    const float* p_hard  = (const float*)d_in[11];

    W15 wk;
    {
        double g[15], sum = 0.0;
        for (int i = 0; i < 15; ++i) { double d = (double)(i - 7); g[i] = exp(-d * d / 18.0); sum += g[i]; }
        for (int i = 0; i < 15; ++i) wk.w[i] = (float)(g[i] / sum);
    }

    // Single fused kernel: x -> out
    dim3 grid(WW / TW, HH / TH, NPLANES);   // 16 x 16 x 12 (remapped in-kernel)
    k_fused<<<grid, dim3(512), 0, stream>>>(
        x, (float*)d_out, gains, p_gamma, p_sb, p_hr, p_br, p_ct,
        p_enh, p_soft, p_int, p_rot, p_hard, wk);
}

// Round 11
// 174.773 us; speedup vs baseline: 1.0526x; 1.0037x over previous
//
#include <hip/hip_runtime.h>
#include <math.h>

#define HH 1024
#define WW 1024
#define NPLANES 12              // B*C = 4*3
#define PLANE (HH * WW)

#define TW 64                   // output tile width
#define TH 64                   // output tile height
#define RH 92                   // h1 rows: gy in [y0-14, y0+77]  (phys rows 0..91)
#define RB 78                   // B1/h2 logical rows: gy in [y0-7, y0+70]
#define PH 80                   // H pitch (floats), 20 quads
// LDS map (floats):
//   [0      .. 7359 ]  H     : h1 rows 0..91 (pitch 80); later h2 in rows 0..77
//   [7360   .. 12479]  B1    : logical rows 0..63 at phys 92..155 (pitch 80);
//                              logical rows 64..77 ALIAS H phys rows 78..91
//   [7360   .. 11775]  A     : 46 x 96 chained-input staging (two passes);
//                              dead before P3 writes B1 (barrier-separated).
#define AOFF 7360
#define APITCH 96               // 24 quads = 3 FULL 8-quad groups
#define LDSF (156 * PH)         // 49,920 B -> 50,176 alloc -> 3 blocks/CU @512thr

struct W15 { float w[15]; };

// ---- H swizzle (pitch 20 quads, PARTIAL last group): 2-bit XOR within aligned
// 4-quad groups — in-range by construction (R9-verified). R10's 3-bit XOR was
// OUT OF RANGE for quads 16..19 (wrote past row end) -> correctness bug.
__device__ inline int swq(int pr, int q) { return pr * PH + ((q ^ (pr & 3)) << 2); }
__device__ inline int sws(int pr, int j) {
    return pr * PH + ((((j >> 2) ^ (pr & 3)) << 2) | (j & 3));
}
// ---- A swizzle (pitch 24 quads = 3 FULL groups): 3-term perm
//   perm(q,r) = (q&24) | ((q ^ (q>>3) ^ r) & 7)
// bijective & in-range per row (XOR-const within each full 8-group); the q>>3
// term makes the 5-seg read set {i,4+i,8+i,12+i,16+i} hit 5 DISTINCT quad-banks
// (fixes hblur's 3-way conflict that appeared with R9's A).
__device__ inline int aperm(int q, int r) {
    return (q & 24) | ((q ^ (q >> 3) ^ r) & 7);
}
__device__ inline int aq(int r, int q) {
    return AOFF + r * APITCH + (aperm(q, r) << 2);
}
__device__ inline int as(int r, int c) {
    return AOFF + r * APITCH + ((aperm(c >> 2, r) << 2) | (c & 3));
}
// B1 logical row -> physical LDS row
__device__ inline int b1r(int r) { return (r < 64) ? (92 + r) : (r + 14); }

// pointwise chain with pre-folded constants:
//   k2 = sb+hr ; kc = 0.5 + br - 0.5*ct
__device__ inline float chain1(float t, float gain, float gamma, float sb,
                               float k2, float ct, float kc) {
    t = t * gain;
    t = __builtin_amdgcn_exp2f(gamma * __log2f(t));          // pow(t,gamma), t>=0
    float hi = __fdividef(1.0f, 1.0f + __expf((0.5f - t) * 10.0f));
    t = fmaf(-k2, hi, t + sb);                               // t + sb*(1-hi) - hr*hi
    t = fminf(fmaxf(t, 0.0f), 1.0f);
    t = fmaf(ct, t, kc);                                     // ct*(t-0.5)+0.5+br
    return fminf(fmaxf(t, 0.0f), 1.0f);
}

// 16 outputs from a 32-float register window; output j taps f[j+1 .. j+15]
__device__ inline void dot16(const float* f, const W15& wk, float* o) {
#pragma unroll
    for (int j = 0; j < 16; ++j) {
        float a = 0.0f, b = 0.0f;
#pragma unroll
        for (int k = 0; k < 8; ++k)  a += wk.w[k] * f[j + 1 + k];
#pragma unroll
        for (int k = 8; k < 15; ++k) b += wk.w[k] * f[j + 1 + k];
        o[j] = a + b;
    }
}

// ---- XCD-aware tile remap: same-XCD (mod-8) blocks cover contiguous region ---
__device__ inline void tile_map(int& p, int& x0, int& y0, bool& edge) {
    int L = (blockIdx.z * gridDim.y + blockIdx.y) * gridDim.x + blockIdx.x; // 0..3071
    int xcd = L & 7;
    int t   = L >> 3;
    int g   = xcd * 384 + t;          // contiguous 1.5-plane region per XCD
    p = g >> 8;
    int w  = g & 255;
    int ty = w >> 4, tx = w & 15;
    x0 = tx * TW; y0 = ty * TH;
    edge = (tx == 0) || (tx == 15) || (ty == 0) || (ty == 15);
}

// P0: chain(x) for one 46-row vertical half into A (zero outside image)
__device__ inline void stage_A(float* lds, const float* __restrict__ plane,
                               int x0, int gyb, bool edge, int tid,
                               float gain, float gamma, float sb,
                               float k2, float ct, float kc) {
#pragma unroll
    for (int k = 0; k < 2; ++k) {
        int u = tid + 512 * k;                   // < 1024 < 1104, always active
        int r = u / 24, q = u - 24 * r;
        int gy = gyb + r;
        int gq = x0 - 16 + 4 * q;                // 4-aligned: quad all-in/all-out
        float4 v = make_float4(0.f, 0.f, 0.f, 0.f);
        if (!edge || ((unsigned)gy < HH && gq >= 0 && gq + 3 < WW)) {
            v = *(const float4*)(plane + (size_t)gy * WW + gq);
            float* pv = (float*)&v;
#pragma unroll
            for (int j = 0; j < 4; ++j)
                pv[j] = chain1(pv[j], gain, gamma, sb, k2, ct, kc);
        }
        *(float4*)&lds[aq(r, q)] = v;
    }
    if (tid < 46 * 24 - 1024) {                  // tail: 80 threads
        int u = tid + 1024;
        int r = u / 24, q = u - 24 * r;
        int gy = gyb + r;
        int gq = x0 - 16 + 4 * q;
        float4 v = make_float4(0.f, 0.f, 0.f, 0.f);
        if (!edge || ((unsigned)gy < HH && gq >= 0 && gq + 3 < WW)) {
            v = *(const float4*)(plane + (size_t)gy * WW + gq);
            float* pv = (float*)&v;
#pragma unroll
            for (int j = 0; j < 4; ++j)
                pv[j] = chain1(pv[j], gain, gamma, sb, k2, ct, kc);
        }
        *(float4*)&lds[aq(r, q)] = v;
    }
}

// P1: h1 rows (one 46-row half) from A; no edge handling needed (A zero-padded)
__device__ inline void hblur_half(float* lds, int hrow0, int tid, const W15& wk) {
    if (tid < 46 * 5) {
        int r = tid / 5, s = tid - 5 * r;        // A row r, out cols 16s..16s+15
        float f[32];
#pragma unroll
        for (int i = 0; i < 8; ++i)
            *(float4*)&f[4 * i] = *(const float4*)&lds[aq(r, 4 * s + i)];
        float o[16];
        dot16(f, wk, o);
        int hr_ = hrow0 + r;
#pragma unroll
        for (int qq = 0; qq < 4; ++qq)
            *(float4*)&lds[swq(hr_, 4 * s + qq)] = *(float4*)&o[4 * qq];
    }
}

// =============================================================================
// Fully fused single kernel (512 threads, 64x64 tile, 3 blocks/CU):
//  P0a: chain(x) rows y0-14..y0+31 -> A      | bar
//  P1a: h1 rows 0..45 = hblur(A); cc for ty<4 from A | bar
//  P0b: chain(x) rows y0+32..y0+77 -> A      | bar
//  P1b: h1 rows 46..91; cc for ty>=4 from A  | bar
//  P3 : B1 = vblur(h1) masked to image (5 bands; band 4 owns aliased rows) | bar
//  P4 : h2 = hblur(B1) -> H rows 0..77       | bar
//  P5 : B2 = vblur(h2); x2c=(1+e)cc-e*bb; bx2=(1+e)bb-e*B2;
//       out = clip((s*bx2+(1-s)*x2c)*(1-intensity*mask)), NT store
// =============================================================================
__global__ __launch_bounds__(512, 6) void k_fused(
    const float* __restrict__ x, float* __restrict__ dst,
    const float* __restrict__ gains,
    const float* __restrict__ pg, const float* __restrict__ psb,
    const float* __restrict__ phr, const float* __restrict__ pbr,
    const float* __restrict__ pct, const float* __restrict__ penh,
    const float* __restrict__ psoft, const float* __restrict__ pint,
    const float* __restrict__ prot, const float* __restrict__ phard,
    W15 wk)
{
    __shared__ float lds[LDSF];

    int p, x0, y0; bool edge;
    tile_map(p, x0, y0, edge);
    const int tid = threadIdx.x;
    const int tx  = tid & 63;
    const int ty  = tid >> 6;            // 0..7

    const float* __restrict__ plane = x + (size_t)p * PLANE;
    const float gain  = gains[p % 3];
    const float gamma = *pg, sb = *psb, hrp = *phr, br = *pbr, ct = *pct;
    const float k2 = sb + hrp;
    const float kc = 0.5f + br - 0.5f * ct;

    float cc[8];

    // ---------------- P0a / P1a (+cc rows 0..31) ------------------------------
    stage_A(lds, plane, x0, y0 - 14, edge, tid, gain, gamma, sb, k2, ct, kc);
    __syncthreads();
    hblur_half(lds, 0, tid, wk);
    if (ty < 4) {                        // centers gy = y0 + ty*8 + jj, A row +14
#pragma unroll
        for (int jj = 0; jj < 8; ++jj)
            cc[jj] = lds[as(ty * 8 + jj + 14, tx + 16)];
    }
    __syncthreads();

    // ---------------- P0b / P1b (+cc rows 32..63) -----------------------------
    stage_A(lds, plane, x0, y0 + 32, edge, tid, gain, gamma, sb, k2, ct, kc);
    __syncthreads();
    hblur_half(lds, 46, tid, wk);
    if (ty >= 4) {                       // A row = ty*8 + jj + 14 - 46
#pragma unroll
        for (int jj = 0; jj < 8; ++jj)
            cc[jj] = lds[as(ty * 8 + jj - 32, tx + 16)];
    }
    __syncthreads();

    // ---------------- P3: B1 = vblur(h1), masked to image support -------------
    // bands {16,16,16,16,14}: bands 0..3 cover rl 0..63 (write phys 92..155,
    // read rows <= 77); band 4 covers rl 64..77 (reads rows 64..91; each write
    // to phys rl+14 follows this thread's read of that same row/col — address
    // identity holds since both use sws with the same row/col).
    if (tid < 400) {
        int j = tid % 80, band = tid / 80;
        int rb0 = band * 16;                 // 0,16,32,48,64
        int nb  = (band == 4) ? 14 : 16;
        bool xin = (unsigned)(x0 - 8 + j) < WW;
        float win[15];
#pragma unroll
        for (int k = 0; k < 14; ++k) win[k] = lds[sws(rb0 + k, j)];
#pragma unroll
        for (int jj = 0; jj < 16; ++jj) {
            if (jj < nb) {
                win[(jj + 14) % 15] = lds[sws(rb0 + jj + 14, j)];
                float a = 0.0f, b = 0.0f;
#pragma unroll
                for (int k = 0; k < 8; ++k)  a += wk.w[k] * win[(jj + k) % 15];
#pragma unroll
                for (int k = 8; k < 15; ++k) b += wk.w[k] * win[(jj + k) % 15];
                float v = a + b;
                if (edge) {
                    int gy = y0 - 7 + rb0 + jj;
                    if (!((unsigned)gy < HH) || !xin) v = 0.0f;
                }
                lds[sws(b1r(rb0 + jj), j)] = v;
            }
        }
    }
    __syncthreads();

    // ---------------- P4: h2 = hblur(B1) -> rows 0..77, quads 0..15 -----------
    if (tid < RB * 4) {
        int rb = tid >> 2, s = tid & 3;      // out cols gx = x0 + 16s + j
        int pb = b1r(rb);
        float f[32];
#pragma unroll
        for (int i = 0; i < 8; ++i)
            *(float4*)&f[4 * i] = *(const float4*)&lds[swq(pb, 4 * s + i)];
        float o[16];
        dot16(f, wk, o);
#pragma unroll
        for (int qq = 0; qq < 4; ++qq)
            *(float4*)&lds[swq(rb, 4 * s + qq)] = *(float4*)&o[4 * qq];
    }
    __syncthreads();

    // ---------------- P5: B2 = vblur(h2); combine + mask + clip + store -------
    const float e     = *penh;
    const float sf    = *psoft;
    const float inten = *pint;
    const float hard  = *phard;
    const float theta = (*prot) * 0.017453292519943295f;
    const float cth = __cosf(theta), sth = __sinf(theta);
    const int   gx    = x0 + tx;
    const float gbase = (-1.0f + 2.0f * (float)gx * (1.0f / (float)(WW - 1))) * cth;
    const float ce    = 1.0f + e;

    // gradient-mask exp is linear in y -> geometric recurrence (1 exp, 7 muls)
    const float dstep = 2.0f / (float)(HH - 1);
    const float gy0n  = -1.0f + (float)(y0 + ty * 8) * dstep;
    float       E     = __expf(hard * (gbase + gy0n * sth));
    const float q     = __expf(hard * sth * dstep);

    const int ry0 = ty * 8;

    float bb[8];
#pragma unroll
    for (int jj = 0; jj < 8; ++jj)
        bb[jj] = lds[sws(b1r(ry0 + jj + 7), tx + 8)];

    float win[15];
#pragma unroll
    for (int k = 0; k < 14; ++k) win[k] = lds[sws(ry0 + k, tx)];

    float* __restrict__ dstP = dst + (size_t)p * PLANE;
#pragma unroll
    for (int jj = 0; jj < 8; ++jj) {
        win[(jj + 14) % 15] = lds[sws(ry0 + jj + 14, tx)];
        float a = 0.0f, b = 0.0f;
#pragma unroll
        for (int k = 0; k < 8; ++k)  a += wk.w[k] * win[(jj + k) % 15];
#pragma unroll
        for (int k = 8; k < 15; ++k) b += wk.w[k] * win[(jj + k) % 15];
        float B2  = a + b;
        float x2c = ce * cc[jj] - e * bb[jj];       // x2 at center
        float bx2 = ce * bb[jj] - e * B2;           // blur(x2) via linearity
        float v   = sf * bx2 + (1.0f - sf) * x2c;
        int   y   = y0 + ry0 + jj;
        float mask = __fdividef(1.0f, 1.0f + E);
        E *= q;
        v = v * (1.0f - inten * mask);
        v = fminf(fmaxf(v, 0.0f), 1.0f);
        __builtin_nontemporal_store(v, &dstP[(size_t)y * WW + gx]);
    }
}

extern "C" void kernel_launch(void* const* d_in, const int* in_sizes, int n_in,
                              void* d_out, int out_size, void* d_ws, size_t ws_size,
                              hipStream_t stream)
{
    const float* x       = (const float*)d_in[0];
    const float* gains   = (const float*)d_in[1];
    const float* p_gamma = (const float*)d_in[2];
    const float* p_sb    = (const float*)d_in[3];
    const float* p_hr    = (const float*)d_in[4];
    const float* p_br    = (const float*)d_in[5];
    const float* p_ct    = (const float*)d_in[6];
    const float* p_enh   = (const float*)d_in[7];
    const float* p_soft  = (const float*)d_in[8];
    const float* p_int   = (const float*)d_in[9];
    const float* p_rot   = (const float*)d_in[10];
    const float* p_hard  = (const float*)d_in[11];

    W15 wk;
    {
        double g[15], sum = 0.0;
        for (int i = 0; i < 15; ++i) { double d = (double)(i - 7); g[i] = exp(-d * d / 18.0); sum += g[i]; }
        for (int i = 0; i < 15; ++i) wk.w[i] = (float)(g[i] / sum);
    }

    // Single fused kernel: x -> out (no workspace -> no ws-poison overhead)
    dim3 grid(WW / TW, HH / TH, NPLANES);   // 16 x 16 x 12 (remapped in-kernel)
    k_fused<<<grid, dim3(512), 0, stream>>>(
        x, (float*)d_out, gains, p_gamma, p_sb, p_hr, p_br, p_ct,
        p_enh, p_soft, p_int, p_rot, p_hard, wk);
}